// Round 2
// baseline (140.314 us; speedup 1.0000x reference)
//
#include <hip/hip_runtime.h>

// Problem constants (fixed by setup_inputs): B=64, T=1024, V=128, S=256
constexpr int B_ = 64;
constexpr int T_ = 1024;
constexpr int V_ = 128;
constexpr int S_ = 256;
constexpr int GRING = 32;            // staged rows per direction (8 blocks of 4)
constexpr int ROWF = 384;            // floats per staged row: 3 planes x 64 lanes x float2
constexpr int NGW = 3;               // gather waves per direction (cheap coalesced gather)
constexpr float INV_LN2 = 1.4426950408889634f;
constexpr float LN2 = 0.6931471805599453f;

#define WG_SCOPE __HIP_MEMORY_SCOPE_WORKGROUP

__device__ __forceinline__ void poll_eq(int* p, int want) {
    // RELAXED: LDS is physically shared per-CU; producer drained its ds_writes
    // (explicit lgkmcnt(0)) before the tag became visible.
    while (__hip_atomic_load(p, __ATOMIC_RELAXED, WG_SCOPE) != want)
        __builtin_amdgcn_s_sleep(1);
}

// Wave-uniform butterfly rescale: pin wave max to 2^124 (R8-proven: with
// worst realistic decay ~12.6 bits/row, floor after 8 rows stays > 2^20).
// R9 LESSON: 16-row period with fixed mid-boost flushes to denormal->0.
__device__ __forceinline__ int wave_rescale(float a[10], int& K) {
    float mx = a[0];
    #pragma unroll
    for (int k = 1; k < 10; ++k) mx = fmaxf(mx, a[k]);
    #pragma unroll
    for (int d = 1; d < 64; d <<= 1) mx = fmaxf(mx, __shfl_xor(mx, d, 64));
    int e;
    (void)frexpf(mx, &e);
    const int ks = (mx > 0.0f) ? (124 - e) : 0;
    #pragma unroll
    for (int k = 0; k < 10; ++k) a[k] = ldexpf(a[k], ks);
    K += ks;
    return ks;
}

// Fused: 1 block / batch element. wave0 = forward alpha, wave1 = backward beta,
// waves 2..4 = fwd gatherers, 5..7 = bwd gatherers. Linear domain, wave-uniform K.
// R10/R11: gatherers load the FULL 512B row coalesced (1 dwordx2/lane), exp2 only
// the 2 owned values, and gather label positions in-register via ds_bpermute
// (__shfl). 2-block-deep intra-wave prefetch; tag store is lgkmcnt-drain +
// RELAXED so in-flight global loads survive the tag publish.
__global__ __launch_bounds__(512) void ctc_fused7(
    const float* __restrict__ lp,      // [B,T,V] natural-log softmax
    const int* __restrict__ in_len,    // [B]
    const int* __restrict__ tgt,       // [B,S]
    const int* __restrict__ tgt_len,   // [B]
    float* __restrict__ ws)            // [B] per-batch loss / L
{
    const int b    = blockIdx.x;
    const int tid  = threadIdx.x;
    const int wid  = tid >> 6;
    const int lane = tid & 63;

    __shared__ float ringF[GRING * ROWF];    // 48 KB
    __shared__ float ringB[GRING * ROWF];    // 48 KB
    __shared__ float dumpA[640];
    __shared__ float dumpB[640];
    __shared__ int   tagF[8], tagB[8];
    __shared__ int   consF, consB;
    __shared__ int   KFsh, KBsh;

    const int L  = tgt_len[b];        // 64..256
    const int Tb = in_len[b];         // 768..1024
    const float* lpb = lp + (size_t)b * T_ * V_;
    const int* tg = tgt + b * S_;

    const int tm = (Tb - 2) >> 1;
    const int Uf = tm;                // fwd steps: u=1..Uf (row t=u) -> alpha_tm
    const int Ub = Tb - 2 - tm;       // bwd steps: u=1..Ub (row t=Tb-1-u) -> g_{tm+1}

    if (tid == 0) { consF = 0; consB = 0; }
    if (tid < 8) tagF[tid] = -1;
    else if (tid < 16) tagB[tid - 8] = -1;
    __syncthreads();

    if (wid >= 2) {
        // ======================= gatherers =======================
        const int gw  = wid - 2;                   // 0..5
        const int dir = gw / NGW;                  // 0 = fwd, 1 = bwd
        const int q   = gw % NGW;
        const int U   = dir ? Ub : Uf;
        float* ring   = dir ? ringB : ringF;
        int*   tags   = dir ? tagB  : tagF;
        int*   consp  = dir ? &consB : &consF;

        // label -> (source lane, component) for in-register gather of exp-row
        int   perm[5], oddc[5];
        float vmask[5];
        #pragma unroll
        for (int c = 0; c < 5; ++c) {
            const int j = 5 * lane + c;
            if (j < L) { const int lb = tg[j]; perm[c] = lb >> 1; oddc[c] = lb & 1; vmask[c] = 1.0f; }
            else       { perm[c] = 0; oddc[c] = 0; vmask[c] = 0.0f; }
        }

        float2 R0[4], R1[4];
        auto issue = [&](float2 (&Rb)[4], int m) {
            const int n = min(4, U - 4 * m);
            #pragma unroll
            for (int r = 0; r < 4; ++r) {
                if (r < n) {
                    const int u = 4 * m + 1 + r;
                    const int t = dir ? (Tb - 1 - u) : u;
                    Rb[r] = *(const float2*)(lpb + (size_t)t * V_ + 2 * lane);
                }
            }
        };
        // block m covers rows u = 4m+1 .. 4m+4; row u lives at slot (u-1)&31
        auto process = [&](float2 (&Rb)[4], int m) {
            // ring-slot reuse gate: slot shared with block m-8
            while (__hip_atomic_load(consp, __ATOMIC_RELAXED, WG_SCOPE) < 4 * m - 28)
                __builtin_amdgcn_s_sleep(1);
            const int n = min(4, U - 4 * m);
            #pragma unroll
            for (int r = 0; r < 4; ++r) {
                if (r < n) {
                    const float e0 = __builtin_exp2f(Rb[r].x * INV_LN2);
                    const float e1 = __builtin_exp2f(Rb[r].y * INV_LN2);
                    const float b0 = __shfl(e0, 0, 64);      // blank = exp(row[0])
                    float gv[5];
                    #pragma unroll
                    for (int c = 0; c < 5; ++c) {
                        const float lo = __shfl(e0, perm[c], 64);
                        const float hi = __shfl(e1, perm[c], 64);
                        gv[c] = vmask[c] * (oddc[c] ? hi : lo);
                    }
                    float* rb = ring + ((4 * m + r) & (GRING - 1)) * ROWF;
                    ((float2*)rb)[lane]         = make_float2(b0,    gv[0]);
                    ((float2*)(rb + 128))[lane] = make_float2(gv[1], gv[2]);
                    ((float2*)(rb + 256))[lane] = make_float2(gv[3], gv[4]);
                }
            }
            // drain LDS writes only (NOT vmcnt -- prefetched global loads stay
            // in flight), then publish the tag.
            asm volatile("s_waitcnt lgkmcnt(0)" ::: "memory");
            if (lane == 0)
                __hip_atomic_store(&tags[m & 7], m, __ATOMIC_RELAXED, WG_SCOPE);
        };

        int m = q;
        if (4 * m + 1 <= U) {
            issue(R0, m);
            if (4 * (m + NGW) + 1 <= U) issue(R1, m + NGW);
            while (true) {
                process(R0, m);
                if (4 * (m + 2 * NGW) + 1 <= U) issue(R0, m + 2 * NGW);
                m += NGW;
                if (4 * m + 1 > U) break;
                process(R1, m);
                if (4 * (m + 2 * NGW) + 1 <= U) issue(R1, m + 2 * NGW);
                m += NGW;
                if (4 * m + 1 > U) break;
            }
        }
    } else if (wid == 0) {
        // ======================= forward consumer =======================
        float skipf[5];
        #pragma unroll
        for (int c = 0; c < 5; ++c) {
            const int j = 5 * lane + c;
            skipf[c] = (j >= 1 && j < L && tg[j] != tg[j - 1]) ? 1.0f : 0.0f;
        }
        float a[10];
        #pragma unroll
        for (int k = 0; k < 10; ++k) a[k] = 0.0f;
        {
            const float p00 = __builtin_exp2f(lpb[0] * INV_LN2);
            const float p01 = __builtin_exp2f(lpb[tg[0]] * INV_LN2);
            if (lane == 0) { a[0] = p00; a[1] = p01; }
        }
        float u9n = 0.0f;                 // inflow alpha_prev[s-1] for s=10*lane
        int K = 0;

        float2 S[4][12];                  // [set][row*3+plane], all const-indexed
        auto readBlock = [&](int set, int m) {
            const int base = ((4 * m) & (GRING - 1)) * ROWF + 2 * lane;
            #pragma unroll
            for (int r = 0; r < 4; ++r)
                #pragma unroll
                for (int pl = 0; pl < 3; ++pl)
                    S[set][r * 3 + pl] =
                        *(const float2*)&ringF[base + r * ROWF + pl * 128];
        };
        auto rowCore = [&](float2 c0, float2 c1, float2 c2) {
            const float u9 = u9n;
            const float p0 = c0.x;
            a[9] = (a[9] + a[8] + skipf[4] * a[7]) * c2.y;
            const float t9 = __shfl_up(a[9], 1, 64);   // early-produce
            u9n = (lane == 0) ? 0.0f : t9;
            a[8] = (a[8] + a[7]) * p0;
            a[7] = (a[7] + a[6] + skipf[3] * a[5]) * c2.x;
            a[6] = (a[6] + a[5]) * p0;
            a[5] = (a[5] + a[4] + skipf[2] * a[3]) * c1.y;
            a[4] = (a[4] + a[3]) * p0;
            a[3] = (a[3] + a[2] + skipf[1] * a[1]) * c1.x;
            a[2] = (a[2] + a[1]) * p0;
            a[1] = (a[1] + a[0] + skipf[0] * u9) * c0.y;   // late-consume
            a[0] = (a[0] + u9) * p0;
        };
        auto row4 = [&](int set) {
            #pragma unroll
            for (int r = 0; r < 4; ++r)
                rowCore(S[set][r * 3], S[set][r * 3 + 1], S[set][r * 3 + 2]);
        };
        auto body = [&](int m, int setc, int setp) {
            if (4 * (m + 2) + 1 <= Uf) {
                poll_eq(&tagF[(m + 2) & 7], m + 2);
                readBlock(setp, m + 2);
            }
            row4(setc);
            if (lane == 0)
                __hip_atomic_store(&consF, 4 * m + 4, __ATOMIC_RELAXED, WG_SCOPE);
        };

        const int MB4 = (Uf / 4) & ~3;
        poll_eq(&tagF[0], 0); readBlock(0, 0);
        poll_eq(&tagF[1], 1); readBlock(1, 1);
        for (int mb = 0; mb < MB4; mb += 4) {
            body(mb + 0, 0, 2);
            body(mb + 1, 1, 3);
            { const int ks = wave_rescale(a, K); u9n = ldexpf(u9n, ks); }  // 8 rows
            body(mb + 2, 2, 0);
            body(mb + 3, 3, 1);
            { const int ks = wave_rescale(a, K); u9n = ldexpf(u9n, ks); }  // 8 rows
        }
        // tail: blocks MB4 (set0), MB4+1 (set1) partially, then direct ring rows
        #pragma unroll
        for (int r = 0; r < 4; ++r)
            if (4 * MB4 + 1 + r <= Uf)
                rowCore(S[0][r * 3], S[0][r * 3 + 1], S[0][r * 3 + 2]);
        #pragma unroll
        for (int r = 0; r < 4; ++r)
            if (4 * MB4 + 5 + r <= Uf)
                rowCore(S[1][r * 3], S[1][r * 3 + 1], S[1][r * 3 + 2]);
        { const int ks = wave_rescale(a, K); u9n = ldexpf(u9n, ks); }      // <=8 rows
        for (int u = 4 * MB4 + 9; u <= Uf; ++u) {                          // <=7 rows
            const int bu = (u - 1) >> 2;
            poll_eq(&tagF[bu & 7], bu);
            const int base = ((u - 1) & (GRING - 1)) * ROWF + 2 * lane;
            const float2 c0 = *(const float2*)&ringF[base];
            const float2 c1 = *(const float2*)&ringF[base + 128];
            const float2 c2 = *(const float2*)&ringF[base + 256];
            rowCore(c0, c1, c2);
        }

        #pragma unroll
        for (int k = 0; k < 10; ++k) dumpA[10 * lane + k] = a[k];
        if (lane == 0) {
            KFsh = K;
            __hip_atomic_store(&consF, Uf + 64, __ATOMIC_RELAXED, WG_SCOPE);
        }
    } else {
        // ======================= backward consumer =======================
        float sB[5];                  // skip into s+2 (odd): label j = 5*lane+c+1
        #pragma unroll
        for (int c = 0; c < 5; ++c) {
            const int j = 5 * lane + c + 1;
            sB[c] = (j < L && tg[j] != tg[j - 1]) ? 1.0f : 0.0f;
        }
        float g[10];
        #pragma unroll
        for (int k = 0; k < 10; ++k) g[k] = 0.0f;
        {   // g_{Tb-1}: nonzero at s=2L (blank) and s=2L-1 (last label)
            const float pb = __builtin_exp2f(lpb[(size_t)(Tb - 1) * V_] * INV_LN2);
            const float pl = __builtin_exp2f(lpb[(size_t)(Tb - 1) * V_ + tg[L - 1]] * INV_LN2);
            #pragma unroll
            for (int k = 0; k < 10; ++k) {
                const int s = 10 * lane + k;
                if (s == 2 * L)     g[k] = pb;
                if (s == 2 * L - 1) g[k] = pl;
            }
        }
        float t0 = __shfl_down(g[0], 1, 64), t1 = __shfl_down(g[1], 1, 64);
        float d0n = (lane == 63) ? 0.0f : t0;
        float d1n = (lane == 63) ? 0.0f : t1;
        int K = 0;

        float2 S[4][12];
        auto readBlock = [&](int set, int m) {
            const int base = ((4 * m) & (GRING - 1)) * ROWF + 2 * lane;
            #pragma unroll
            for (int r = 0; r < 4; ++r)
                #pragma unroll
                for (int pl = 0; pl < 3; ++pl)
                    S[set][r * 3 + pl] =
                        *(const float2*)&ringB[base + r * ROWF + pl * 128];
        };
        auto rowCore = [&](float2 c0, float2 c1, float2 c2) {
            const float d0 = d0n, d1 = d1n;
            const float p0 = c0.x;
            g[0] = (g[0] + g[1]) * p0;
            g[1] = (g[1] + g[2] + sB[0] * g[3]) * c0.y;
            const float q0 = __shfl_down(g[0], 1, 64);   // early-produce
            const float q1 = __shfl_down(g[1], 1, 64);
            d0n = (lane == 63) ? 0.0f : q0;
            d1n = (lane == 63) ? 0.0f : q1;
            g[2] = (g[2] + g[3]) * p0;
            g[3] = (g[3] + g[4] + sB[1] * g[5]) * c1.x;
            g[4] = (g[4] + g[5]) * p0;
            g[5] = (g[5] + g[6] + sB[2] * g[7]) * c1.y;
            g[6] = (g[6] + g[7]) * p0;
            g[7] = (g[7] + g[8] + sB[3] * g[9]) * c2.x;
            g[8] = (g[8] + g[9]) * p0;
            g[9] = (g[9] + d0 + sB[4] * d1) * c2.y;      // late-consume
        };
        auto row4 = [&](int set) {
            #pragma unroll
            for (int r = 0; r < 4; ++r)
                rowCore(S[set][r * 3], S[set][r * 3 + 1], S[set][r * 3 + 2]);
        };
        auto body = [&](int m, int setc, int setp) {
            if (4 * (m + 2) + 1 <= Ub) {
                poll_eq(&tagB[(m + 2) & 7], m + 2);
                readBlock(setp, m + 2);
            }
            row4(setc);
            if (lane == 0)
                __hip_atomic_store(&consB, 4 * m + 4, __ATOMIC_RELAXED, WG_SCOPE);
        };

        const int MB4 = (Ub / 4) & ~3;
        poll_eq(&tagB[0], 0); readBlock(0, 0);
        poll_eq(&tagB[1], 1); readBlock(1, 1);
        for (int mb = 0; mb < MB4; mb += 4) {
            body(mb + 0, 0, 2);
            body(mb + 1, 1, 3);
            { const int ks = wave_rescale(g, K);
              d0n = ldexpf(d0n, ks); d1n = ldexpf(d1n, ks); }
            body(mb + 2, 2, 0);
            body(mb + 3, 3, 1);
            { const int ks = wave_rescale(g, K);
              d0n = ldexpf(d0n, ks); d1n = ldexpf(d1n, ks); }
        }
        #pragma unroll
        for (int r = 0; r < 4; ++r)
            if (4 * MB4 + 1 + r <= Ub)
                rowCore(S[0][r * 3], S[0][r * 3 + 1], S[0][r * 3 + 2]);
        #pragma unroll
        for (int r = 0; r < 4; ++r)
            if (4 * MB4 + 5 + r <= Ub)
                rowCore(S[1][r * 3], S[1][r * 3 + 1], S[1][r * 3 + 2]);
        { const int ks = wave_rescale(g, K);
          d0n = ldexpf(d0n, ks); d1n = ldexpf(d1n, ks); }
        for (int u = 4 * MB4 + 9; u <= Ub; ++u) {
            const int bu = (u - 1) >> 2;
            poll_eq(&tagB[bu & 7], bu);
            const int base = ((u - 1) & (GRING - 1)) * ROWF + 2 * lane;
            const float2 c0 = *(const float2*)&ringB[base];
            const float2 c1 = *(const float2*)&ringB[base + 128];
            const float2 c2 = *(const float2*)&ringB[base + 256];
            rowCore(c0, c1, c2);
        }

        {   // combine: gext[s] = g[s] + g[s+1] + skip[s+2]*g[s+2] (ascending)
            const float d0 = d0n, d1 = d1n;
            g[0] = g[0] + g[1];
            g[1] = g[1] + g[2] + sB[0] * g[3];
            g[2] = g[2] + g[3];
            g[3] = g[3] + g[4] + sB[1] * g[5];
            g[4] = g[4] + g[5];
            g[5] = g[5] + g[6] + sB[2] * g[7];
            g[6] = g[6] + g[7];
            g[7] = g[7] + g[8] + sB[3] * g[9];
            g[8] = g[8] + g[9];
            g[9] = g[9] + d0 + sB[4] * d1;
        }
        #pragma unroll
        for (int k = 0; k < 10; ++k) dumpB[10 * lane + k] = g[k];
        if (lane == 0) {
            KBsh = K;
            __hip_atomic_store(&consB, Ub + 64, __ATOMIC_RELAXED, WG_SCOPE);
        }
    }

    __syncthreads();
    if (wid == 0) {
        // join in DOUBLE (factors span ~240 bits in f32 frames — R7 lesson)
        double sum = 0.0;
        #pragma unroll
        for (int k = 0; k < 10; ++k)
            sum += (double)dumpA[10 * lane + k] * (double)dumpB[10 * lane + k];
        #pragma unroll
        for (int d = 1; d < 64; d <<= 1) sum += __shfl_xor(sum, d, 64);
        if (lane == 0) {
            float loss = 0.0f;                     // infeasible (sum<=0) -> 0
            if (sum > 0.0) {
                const long long ub = __double_as_longlong(sum);
                const int ex = (int)((ub >> 52) & 2047) - 1023;
                const double f = __longlong_as_double(
                    (ub & 0x000FFFFFFFFFFFFFLL) | 0x3FF0000000000000LL);
                const float ll2 = __builtin_log2f((float)f)
                                + (float)(ex - KFsh - KBsh);
                loss = -(ll2 * LN2);
                if (!(loss <= 1e29f)) loss = 0.0f; // zero_infinity
            }
            ws[b] = loss / (float)L;
        }
    }
}

__global__ void ctc_reduce_kernel(const float* __restrict__ ws, float* __restrict__ out) {
    float v = ws[threadIdx.x];
    #pragma unroll
    for (int o = 32; o > 0; o >>= 1) v += __shfl_down(v, o);
    if (threadIdx.x == 0) out[0] = v / (float)B_;
}

extern "C" void kernel_launch(void* const* d_in, const int* in_sizes, int n_in,
                              void* d_out, int out_size, void* d_ws, size_t ws_size,
                              hipStream_t stream) {
    const float* lp      = (const float*)d_in[0];
    const int*   in_len  = (const int*)d_in[1];
    const int*   tgt     = (const int*)d_in[2];
    const int*   tgt_len = (const int*)d_in[3];
    float* loss = (float*)d_ws;
    float* out  = (float*)d_out;

    ctc_fused7<<<B_, 512, 0, stream>>>(lp, in_len, tgt, tgt_len, loss);
    ctc_reduce_kernel<<<1, 64, 0, stream>>>(loss, out);
}

// Round 3
// 139.614 us; speedup vs baseline: 1.0050x; 1.0050x over previous
//
#include <hip/hip_runtime.h>

// Problem constants (fixed by setup_inputs): B=64, T=1024, V=128, S=256
constexpr int B_ = 64;
constexpr int T_ = 1024;
constexpr int V_ = 128;
constexpr int S_ = 256;
constexpr int GRING = 32;            // staged rows per direction (8 blocks of 4)
constexpr int ROWF = 384;            // floats per staged row: 3 planes x 64 lanes x float2
constexpr int NGW = 3;               // gather waves (cheap coalesced gather)
constexpr float INV_LN2 = 1.4426950408889634f;
constexpr float LN2 = 0.6931471805599453f;

// Workspace layout (floats): [0..63] per-b loss; [64 ..) dumps: fwd b*640,
// then bwd at +64*640; K exponents as ints after that (fwd [b], bwd [64+b]).
#define WS_DUMPF(W, b) ((W) + 64 + (size_t)(b) * 640)
#define WS_DUMPB(W, b) ((W) + 64 + 64 * 640 + (size_t)(b) * 640)
#define WS_KARR(W)     ((int*)((W) + 64 + 2 * 64 * 640))

#define WG_SCOPE __HIP_MEMORY_SCOPE_WORKGROUP

__device__ __forceinline__ void poll_eq(int* p, int want) {
    // RELAXED: LDS is physically shared per-CU; producer drained its ds_writes
    // (explicit lgkmcnt(0)) before the tag became visible.
    while (__hip_atomic_load(p, __ATOMIC_RELAXED, WG_SCOPE) != want)
        __builtin_amdgcn_s_sleep(1);
}

// Wave-uniform butterfly rescale: pin wave max to 2^124 (R8-proven: with
// worst realistic decay ~12.6 bits/row, floor after 8 rows stays > 2^20).
// R9 LESSON: 16-row period with fixed mid-boost flushes to denormal->0.
__device__ __forceinline__ int wave_rescale(float a[10], int& K) {
    float mx = a[0];
    #pragma unroll
    for (int k = 1; k < 10; ++k) mx = fmaxf(mx, a[k]);
    #pragma unroll
    for (int d = 1; d < 64; d <<= 1) mx = fmaxf(mx, __shfl_xor(mx, d, 64));
    int e;
    (void)frexpf(mx, &e);
    const int ks = (mx > 0.0f) ? (124 - e) : 0;
    #pragma unroll
    for (int k = 0; k < 10; ++k) a[k] = ldexpf(a[k], ks);
    K += ks;
    return ks;
}

// R12: ONE DIRECTION PER WORKGROUP. 128 workgroups x 4 waves:
// wave0 = consumer (fwd alpha or bwd beta), waves 1..3 = gatherers.
// Halves every intra-CU shared load (LDS pipe, SIMD pairing, poll traffic)
// vs the 8-wave both-directions workgroup. Join moved to a 3rd kernel.
__global__ __launch_bounds__(256) void ctc_scan(
    const float* __restrict__ lp,      // [B,T,V] natural-log softmax
    const int* __restrict__ in_len,    // [B]
    const int* __restrict__ tgt,       // [B,S]
    const int* __restrict__ tgt_len,   // [B]
    float* __restrict__ W)             // workspace
{
    const int b    = blockIdx.x & 63;
    const int dir  = blockIdx.x >> 6;         // 0 = fwd, 1 = bwd
    const int tid  = threadIdx.x;
    const int wid  = tid >> 6;
    const int lane = tid & 63;

    __shared__ float ring[GRING * ROWF];      // 48 KB
    __shared__ int   tags[8];
    __shared__ int   cons;

    const int L  = tgt_len[b];        // 64..256
    const int Tb = in_len[b];         // 768..1024
    const float* lpb = lp + (size_t)b * T_ * V_;
    const int* tg = tgt + b * S_;

    const int tm = (Tb - 2) >> 1;
    const int Uf = tm;                // fwd steps: u=1..Uf (row t=u) -> alpha_tm
    const int Ub = Tb - 2 - tm;       // bwd steps: u=1..Ub (row t=Tb-1-u) -> g_{tm+1}
    const int U  = dir ? Ub : Uf;

    if (tid == 0) cons = 0;
    if (tid < 8) tags[tid] = -1;
    __syncthreads();

    if (wid >= 1) {
        // ======================= gatherers =======================
        const int q = wid - 1;                    // 0..2

        // label -> (source lane, component) for in-register gather of exp-row
        int   perm[5], oddc[5];
        float vmask[5];
        #pragma unroll
        for (int c = 0; c < 5; ++c) {
            const int j = 5 * lane + c;
            if (j < L) { const int lb = tg[j]; perm[c] = lb >> 1; oddc[c] = lb & 1; vmask[c] = 1.0f; }
            else       { perm[c] = 0; oddc[c] = 0; vmask[c] = 0.0f; }
        }

        float2 R0[4], R1[4];
        auto issue = [&](float2 (&Rb)[4], int m) {
            const int n = min(4, U - 4 * m);
            #pragma unroll
            for (int r = 0; r < 4; ++r) {
                if (r < n) {
                    const int u = 4 * m + 1 + r;
                    const int t = dir ? (Tb - 1 - u) : u;
                    Rb[r] = *(const float2*)(lpb + (size_t)t * V_ + 2 * lane);
                }
            }
        };
        // block m covers rows u = 4m+1 .. 4m+4; row u lives at slot (u-1)&31
        auto process = [&](float2 (&Rb)[4], int m) {
            // ring-slot reuse gate: slot shared with block m-8
            while (__hip_atomic_load(&cons, __ATOMIC_RELAXED, WG_SCOPE) < 4 * m - 28)
                __builtin_amdgcn_s_sleep(1);
            const int n = min(4, U - 4 * m);
            #pragma unroll
            for (int r = 0; r < 4; ++r) {
                if (r < n) {
                    const float e0 = __builtin_exp2f(Rb[r].x * INV_LN2);
                    const float e1 = __builtin_exp2f(Rb[r].y * INV_LN2);
                    const float b0 = __shfl(e0, 0, 64);      // blank = exp(row[0])
                    float gv[5];
                    #pragma unroll
                    for (int c = 0; c < 5; ++c) {
                        const float lo = __shfl(e0, perm[c], 64);
                        const float hi = __shfl(e1, perm[c], 64);
                        gv[c] = vmask[c] * (oddc[c] ? hi : lo);
                    }
                    float* rb = ring + ((4 * m + r) & (GRING - 1)) * ROWF;
                    ((float2*)rb)[lane]         = make_float2(b0,    gv[0]);
                    ((float2*)(rb + 128))[lane] = make_float2(gv[1], gv[2]);
                    ((float2*)(rb + 256))[lane] = make_float2(gv[3], gv[4]);
                }
            }
            // drain LDS writes only (NOT vmcnt -- prefetched global loads stay
            // in flight), then publish the tag.
            asm volatile("s_waitcnt lgkmcnt(0)" ::: "memory");
            if (lane == 0)
                __hip_atomic_store(&tags[m & 7], m, __ATOMIC_RELAXED, WG_SCOPE);
        };

        int m = q;
        if (4 * m + 1 <= U) {
            issue(R0, m);
            if (4 * (m + NGW) + 1 <= U) issue(R1, m + NGW);
            while (true) {
                process(R0, m);
                if (4 * (m + 2 * NGW) + 1 <= U) issue(R0, m + 2 * NGW);
                m += NGW;
                if (4 * m + 1 > U) break;
                process(R1, m);
                if (4 * (m + 2 * NGW) + 1 <= U) issue(R1, m + 2 * NGW);
                m += NGW;
                if (4 * m + 1 > U) break;
            }
        }
        return;
    }

    // ======================= consumer (wave0) =======================
    float2 S[4][12];                  // [set][row*3+plane], all const-indexed
    auto readBlock = [&](int set, int m) {
        const int base = ((4 * m) & (GRING - 1)) * ROWF + 2 * lane;
        #pragma unroll
        for (int r = 0; r < 4; ++r)
            #pragma unroll
            for (int pl = 0; pl < 3; ++pl)
                S[set][r * 3 + pl] =
                    *(const float2*)&ring[base + r * ROWF + pl * 128];
    };

    if (dir == 0) {
        // -------- forward alpha --------
        float skipf[5];
        #pragma unroll
        for (int c = 0; c < 5; ++c) {
            const int j = 5 * lane + c;
            skipf[c] = (j >= 1 && j < L && tg[j] != tg[j - 1]) ? 1.0f : 0.0f;
        }
        float a[10];
        #pragma unroll
        for (int k = 0; k < 10; ++k) a[k] = 0.0f;
        {
            const float p00 = __builtin_exp2f(lpb[0] * INV_LN2);
            const float p01 = __builtin_exp2f(lpb[tg[0]] * INV_LN2);
            if (lane == 0) { a[0] = p00; a[1] = p01; }
        }
        float u9n = 0.0f;                 // inflow alpha_prev[s-1] for s=10*lane
        int K = 0;

        auto rowCore = [&](float2 c0, float2 c1, float2 c2) {
            const float u9 = u9n;
            const float p0 = c0.x;
            a[9] = (a[9] + a[8] + skipf[4] * a[7]) * c2.y;
            const float t9 = __shfl_up(a[9], 1, 64);   // early-produce
            u9n = (lane == 0) ? 0.0f : t9;
            a[8] = (a[8] + a[7]) * p0;
            a[7] = (a[7] + a[6] + skipf[3] * a[5]) * c2.x;
            a[6] = (a[6] + a[5]) * p0;
            a[5] = (a[5] + a[4] + skipf[2] * a[3]) * c1.y;
            a[4] = (a[4] + a[3]) * p0;
            a[3] = (a[3] + a[2] + skipf[1] * a[1]) * c1.x;
            a[2] = (a[2] + a[1]) * p0;
            a[1] = (a[1] + a[0] + skipf[0] * u9) * c0.y;   // late-consume
            a[0] = (a[0] + u9) * p0;
        };
        auto row4 = [&](int set) {
            #pragma unroll
            for (int r = 0; r < 4; ++r)
                rowCore(S[set][r * 3], S[set][r * 3 + 1], S[set][r * 3 + 2]);
        };
        auto body = [&](int m, int setc, int setp) {
            if (4 * (m + 2) + 1 <= Uf) {
                poll_eq(&tags[(m + 2) & 7], m + 2);
                readBlock(setp, m + 2);
            }
            row4(setc);
            if (lane == 0)
                __hip_atomic_store(&cons, 4 * m + 4, __ATOMIC_RELAXED, WG_SCOPE);
        };

        const int MB4 = (Uf / 4) & ~3;
        poll_eq(&tags[0], 0); readBlock(0, 0);
        poll_eq(&tags[1], 1); readBlock(1, 1);
        for (int mb = 0; mb < MB4; mb += 4) {
            body(mb + 0, 0, 2);
            body(mb + 1, 1, 3);
            { const int ks = wave_rescale(a, K); u9n = ldexpf(u9n, ks); }  // 8 rows
            body(mb + 2, 2, 0);
            body(mb + 3, 3, 1);
            { const int ks = wave_rescale(a, K); u9n = ldexpf(u9n, ks); }  // 8 rows
        }
        // tail: blocks MB4 (set0), MB4+1 (set1) partially, then direct ring rows
        #pragma unroll
        for (int r = 0; r < 4; ++r)
            if (4 * MB4 + 1 + r <= Uf)
                rowCore(S[0][r * 3], S[0][r * 3 + 1], S[0][r * 3 + 2]);
        #pragma unroll
        for (int r = 0; r < 4; ++r)
            if (4 * MB4 + 5 + r <= Uf)
                rowCore(S[1][r * 3], S[1][r * 3 + 1], S[1][r * 3 + 2]);
        { const int ks = wave_rescale(a, K); u9n = ldexpf(u9n, ks); }      // <=8 rows
        for (int u = 4 * MB4 + 9; u <= Uf; ++u) {                          // <=7 rows
            const int bu = (u - 1) >> 2;
            poll_eq(&tags[bu & 7], bu);
            const int base = ((u - 1) & (GRING - 1)) * ROWF + 2 * lane;
            const float2 c0 = *(const float2*)&ring[base];
            const float2 c1 = *(const float2*)&ring[base + 128];
            const float2 c2 = *(const float2*)&ring[base + 256];
            rowCore(c0, c1, c2);
        }

        float* dump = WS_DUMPF(W, b);
        #pragma unroll
        for (int k = 0; k < 10; ++k) dump[10 * lane + k] = a[k];
        if (lane == 0) WS_KARR(W)[b] = K;
    } else {
        // -------- backward beta --------
        float sB[5];                  // skip into s+2 (odd): label j = 5*lane+c+1
        #pragma unroll
        for (int c = 0; c < 5; ++c) {
            const int j = 5 * lane + c + 1;
            sB[c] = (j < L && tg[j] != tg[j - 1]) ? 1.0f : 0.0f;
        }
        float g[10];
        #pragma unroll
        for (int k = 0; k < 10; ++k) g[k] = 0.0f;
        {   // g_{Tb-1}: nonzero at s=2L (blank) and s=2L-1 (last label)
            const float pb = __builtin_exp2f(lpb[(size_t)(Tb - 1) * V_] * INV_LN2);
            const float pl = __builtin_exp2f(lpb[(size_t)(Tb - 1) * V_ + tg[L - 1]] * INV_LN2);
            #pragma unroll
            for (int k = 0; k < 10; ++k) {
                const int s = 10 * lane + k;
                if (s == 2 * L)     g[k] = pb;
                if (s == 2 * L - 1) g[k] = pl;
            }
        }
        float t0 = __shfl_down(g[0], 1, 64), t1 = __shfl_down(g[1], 1, 64);
        float d0n = (lane == 63) ? 0.0f : t0;
        float d1n = (lane == 63) ? 0.0f : t1;
        int K = 0;

        auto rowCore = [&](float2 c0, float2 c1, float2 c2) {
            const float d0 = d0n, d1 = d1n;
            const float p0 = c0.x;
            g[0] = (g[0] + g[1]) * p0;
            g[1] = (g[1] + g[2] + sB[0] * g[3]) * c0.y;
            const float q0 = __shfl_down(g[0], 1, 64);   // early-produce
            const float q1 = __shfl_down(g[1], 1, 64);
            d0n = (lane == 63) ? 0.0f : q0;
            d1n = (lane == 63) ? 0.0f : q1;
            g[2] = (g[2] + g[3]) * p0;
            g[3] = (g[3] + g[4] + sB[1] * g[5]) * c1.x;
            g[4] = (g[4] + g[5]) * p0;
            g[5] = (g[5] + g[6] + sB[2] * g[7]) * c1.y;
            g[6] = (g[6] + g[7]) * p0;
            g[7] = (g[7] + g[8] + sB[3] * g[9]) * c2.x;
            g[8] = (g[8] + g[9]) * p0;
            g[9] = (g[9] + d0 + sB[4] * d1) * c2.y;      // late-consume
        };
        auto row4 = [&](int set) {
            #pragma unroll
            for (int r = 0; r < 4; ++r)
                rowCore(S[set][r * 3], S[set][r * 3 + 1], S[set][r * 3 + 2]);
        };
        auto body = [&](int m, int setc, int setp) {
            if (4 * (m + 2) + 1 <= Ub) {
                poll_eq(&tags[(m + 2) & 7], m + 2);
                readBlock(setp, m + 2);
            }
            row4(setc);
            if (lane == 0)
                __hip_atomic_store(&cons, 4 * m + 4, __ATOMIC_RELAXED, WG_SCOPE);
        };

        const int MB4 = (Ub / 4) & ~3;
        poll_eq(&tags[0], 0); readBlock(0, 0);
        poll_eq(&tags[1], 1); readBlock(1, 1);
        for (int mb = 0; mb < MB4; mb += 4) {
            body(mb + 0, 0, 2);
            body(mb + 1, 1, 3);
            { const int ks = wave_rescale(g, K);
              d0n = ldexpf(d0n, ks); d1n = ldexpf(d1n, ks); }
            body(mb + 2, 2, 0);
            body(mb + 3, 3, 1);
            { const int ks = wave_rescale(g, K);
              d0n = ldexpf(d0n, ks); d1n = ldexpf(d1n, ks); }
        }
        #pragma unroll
        for (int r = 0; r < 4; ++r)
            if (4 * MB4 + 1 + r <= Ub)
                rowCore(S[0][r * 3], S[0][r * 3 + 1], S[0][r * 3 + 2]);
        #pragma unroll
        for (int r = 0; r < 4; ++r)
            if (4 * MB4 + 5 + r <= Ub)
                rowCore(S[1][r * 3], S[1][r * 3 + 1], S[1][r * 3 + 2]);
        { const int ks = wave_rescale(g, K);
          d0n = ldexpf(d0n, ks); d1n = ldexpf(d1n, ks); }
        for (int u = 4 * MB4 + 9; u <= Ub; ++u) {
            const int bu = (u - 1) >> 2;
            poll_eq(&tags[bu & 7], bu);
            const int base = ((u - 1) & (GRING - 1)) * ROWF + 2 * lane;
            const float2 c0 = *(const float2*)&ring[base];
            const float2 c1 = *(const float2*)&ring[base + 128];
            const float2 c2 = *(const float2*)&ring[base + 256];
            rowCore(c0, c1, c2);
        }

        {   // combine: gext[s] = g[s] + g[s+1] + skip[s+2]*g[s+2] (ascending)
            const float d0 = d0n, d1 = d1n;
            g[0] = g[0] + g[1];
            g[1] = g[1] + g[2] + sB[0] * g[3];
            g[2] = g[2] + g[3];
            g[3] = g[3] + g[4] + sB[1] * g[5];
            g[4] = g[4] + g[5];
            g[5] = g[5] + g[6] + sB[2] * g[7];
            g[6] = g[6] + g[7];
            g[7] = g[7] + g[8] + sB[3] * g[9];
            g[8] = g[8] + g[9];
            g[9] = g[9] + d0 + sB[4] * d1;
        }
        float* dump = WS_DUMPB(W, b);
        #pragma unroll
        for (int k = 0; k < 10; ++k) dump[10 * lane + k] = g[k];
        if (lane == 0) WS_KARR(W)[64 + b] = K;
    }
}

// Join: one block per batch element, 64 lanes. Double-precision dot of the
// two dumps (factors span ~240 bits in f32 frames -- R7 lesson).
__global__ void ctc_join_kernel(const float* __restrict__ W_const,
                                const int* __restrict__ tgt_len,
                                float* __restrict__ lossArr) {
    const int b = blockIdx.x;
    const int lane = threadIdx.x;
    float* W = const_cast<float*>(W_const);
    const float* dA = WS_DUMPF(W, b);
    const float* dB = WS_DUMPB(W, b);
    double sum = 0.0;
    #pragma unroll
    for (int k = 0; k < 10; ++k)
        sum += (double)dA[10 * lane + k] * (double)dB[10 * lane + k];
    #pragma unroll
    for (int d = 1; d < 64; d <<= 1) sum += __shfl_xor(sum, d, 64);
    if (lane == 0) {
        const int L = tgt_len[b];
        const int KF = WS_KARR(W)[b];
        const int KB = WS_KARR(W)[64 + b];
        float loss = 0.0f;                     // infeasible (sum<=0) -> 0
        if (sum > 0.0) {
            const long long ub = __double_as_longlong(sum);
            const int ex = (int)((ub >> 52) & 2047) - 1023;
            const double f = __longlong_as_double(
                (ub & 0x000FFFFFFFFFFFFFLL) | 0x3FF0000000000000LL);
            const float ll2 = __builtin_log2f((float)f)
                            + (float)(ex - KF - KB);
            loss = -(ll2 * LN2);
            if (!(loss <= 1e29f)) loss = 0.0f; // zero_infinity
        }
        lossArr[b] = loss / (float)L;
    }
}

__global__ void ctc_reduce_kernel(const float* __restrict__ ws, float* __restrict__ out) {
    float v = ws[threadIdx.x];
    #pragma unroll
    for (int o = 32; o > 0; o >>= 1) v += __shfl_down(v, o);
    if (threadIdx.x == 0) out[0] = v / (float)B_;
}

extern "C" void kernel_launch(void* const* d_in, const int* in_sizes, int n_in,
                              void* d_out, int out_size, void* d_ws, size_t ws_size,
                              hipStream_t stream) {
    const float* lp      = (const float*)d_in[0];
    const int*   in_len  = (const int*)d_in[1];
    const int*   tgt     = (const int*)d_in[2];
    const int*   tgt_len = (const int*)d_in[3];
    float* W   = (float*)d_ws;                  // needs ~330 KB
    float* out = (float*)d_out;

    ctc_scan<<<2 * B_, 256, 0, stream>>>(lp, in_len, tgt, tgt_len, W);
    ctc_join_kernel<<<B_, 64, 0, stream>>>(W, tgt_len, W);   // writes W[0..63]
    ctc_reduce_kernel<<<1, 64, 0, stream>>>(W, out);
}

// Round 4
// 126.883 us; speedup vs baseline: 1.1059x; 1.1003x over previous
//
#include <hip/hip_runtime.h>

// Problem constants (fixed by setup_inputs): B=64, T=1024, V=128, S=256
constexpr int B_ = 64;
constexpr int T_ = 1024;
constexpr int V_ = 128;
constexpr int S_ = 256;
constexpr int GRING = 32;            // staged rows per direction (8 blocks of 4)
constexpr int ROWF = 384;            // floats per staged row: 3 planes x 64 lanes x float2
constexpr int NGW = 3;               // gather waves (cheap coalesced gather)
constexpr float INV_LN2 = 1.4426950408889634f;
constexpr float LN2 = 0.6931471805599453f;

// Workspace layout (floats): [0..63] per-b loss; [64 ..) dumps: fwd b*640,
// then bwd at +64*640; K exponents as ints after that (fwd [b], bwd [64+b]).
#define WS_DUMPF(W, b) ((W) + 64 + (size_t)(b) * 640)
#define WS_DUMPB(W, b) ((W) + 64 + 64 * 640 + (size_t)(b) * 640)
#define WS_KARR(W)     ((int*)((W) + 64 + 2 * 64 * 640))

#define WG_SCOPE __HIP_MEMORY_SCOPE_WORKGROUP

// ---- DPP cross-lane helpers (pure VALU: no DS op, no lgkmcnt) ----
// ctrl: 0x110+N row_shr:N, 0x130 wave_shl:1, 0x138 wave_shr:1,
//       0x142 row_bcast:15, 0x143 row_bcast:31
template <int CTRL>
__device__ __forceinline__ float dpp_mov0(float x) {
    // invalid source lanes receive old = 0 (wave_shr1: lane0 -> 0;
    // wave_shl1: lane63 -> 0) -- exactly the boundary fill the scan needs.
    return __int_as_float(__builtin_amdgcn_update_dpp(
        0, __float_as_int(x), CTRL, 0xF, 0xF, false));
}
template <int CTRL>
__device__ __forceinline__ float dpp_max(float x) {
    // invalid lanes fold to old = x (self): max(x,x)=x, harmless.
    const float s = __int_as_float(__builtin_amdgcn_update_dpp(
        __float_as_int(x), __float_as_int(x), CTRL, 0xF, 0xF, false));
    return fmaxf(x, s);
}

__device__ __forceinline__ void poll_eq(int* p, int want) {
    // RELAXED: LDS is physically shared per-CU; producer drained its ds_writes
    // (explicit lgkmcnt(0)) before the tag became visible.
    while (__hip_atomic_load(p, __ATOMIC_RELAXED, WG_SCOPE) != want)
        __builtin_amdgcn_s_sleep(1);
}

// Wave-uniform rescale: pin wave max to 2^124 (R8-proven: with worst
// realistic decay ~12.6 bits/row, floor after 8 rows stays > 2^20).
// R9 LESSON: 16-row period with fixed mid-boost flushes to denormal->0.
// R13: wave-max via DPP reduce (row_shr 1/2/4/8 + bcast15/31 -> lane63)
// + readlane instead of the 6-step ds_bpermute butterfly (~300 cy serial).
__device__ __forceinline__ int wave_rescale(float a[10], int& K) {
    float mx = a[0];
    #pragma unroll
    for (int k = 1; k < 10; ++k) mx = fmaxf(mx, a[k]);
    mx = dpp_max<0x111>(mx);   // row_shr:1
    mx = dpp_max<0x112>(mx);   // row_shr:2
    mx = dpp_max<0x114>(mx);   // row_shr:4
    mx = dpp_max<0x118>(mx);   // row_shr:8  -> lane15 of each row has row-max
    mx = dpp_max<0x142>(mx);   // row_bcast:15
    mx = dpp_max<0x143>(mx);   // row_bcast:31 -> lane63 has wave-max
    const float mall = __int_as_float(
        __builtin_amdgcn_readlane(__float_as_int(mx), 63));
    int e;
    (void)frexpf(mall, &e);
    const int ks = (mall > 0.0f) ? (124 - e) : 0;
    #pragma unroll
    for (int k = 0; k < 10; ++k) a[k] = ldexpf(a[k], ks);
    K += ks;
    return ks;
}

// R12: ONE DIRECTION PER WORKGROUP. 128 workgroups x 4 waves:
// wave0 = consumer (fwd alpha or bwd beta), waves 1..3 = gatherers.
// R13: all per-row cross-lane ops converted ds_bpermute -> DPP so the
// consumer's critical path has NO lgkmcnt stalls (the in-order DS queue
// was serializing the shfl waits behind the 12 prefetch ds_reads).
__global__ __launch_bounds__(256) void ctc_scan(
    const float* __restrict__ lp,      // [B,T,V] natural-log softmax
    const int* __restrict__ in_len,    // [B]
    const int* __restrict__ tgt,       // [B,S]
    const int* __restrict__ tgt_len,   // [B]
    float* __restrict__ W)             // workspace
{
    const int b    = blockIdx.x & 63;
    const int dir  = blockIdx.x >> 6;         // 0 = fwd, 1 = bwd
    const int tid  = threadIdx.x;
    const int wid  = tid >> 6;
    const int lane = tid & 63;

    __shared__ float ring[GRING * ROWF];      // 48 KB
    __shared__ int   tags[8];
    __shared__ int   cons;

    const int L  = tgt_len[b];        // 64..256
    const int Tb = in_len[b];         // 768..1024
    const float* lpb = lp + (size_t)b * T_ * V_;
    const int* tg = tgt + b * S_;

    const int tm = (Tb - 2) >> 1;
    const int Uf = tm;                // fwd steps: u=1..Uf (row t=u) -> alpha_tm
    const int Ub = Tb - 2 - tm;       // bwd steps: u=1..Ub (row t=Tb-1-u) -> g_{tm+1}
    const int U  = dir ? Ub : Uf;

    if (tid == 0) cons = 0;
    if (tid < 8) tags[tid] = -1;
    __syncthreads();

    if (wid >= 1) {
        // ======================= gatherers =======================
        const int q = wid - 1;                    // 0..2

        // label -> (source lane, component) for in-register gather of exp-row
        int   perm[5], oddc[5];
        float vmask[5];
        #pragma unroll
        for (int c = 0; c < 5; ++c) {
            const int j = 5 * lane + c;
            if (j < L) { const int lb = tg[j]; perm[c] = lb >> 1; oddc[c] = lb & 1; vmask[c] = 1.0f; }
            else       { perm[c] = 0; oddc[c] = 0; vmask[c] = 0.0f; }
        }

        float2 R0[4], R1[4];
        auto issue = [&](float2 (&Rb)[4], int m) {
            const int n = min(4, U - 4 * m);
            #pragma unroll
            for (int r = 0; r < 4; ++r) {
                if (r < n) {
                    const int u = 4 * m + 1 + r;
                    const int t = dir ? (Tb - 1 - u) : u;
                    Rb[r] = *(const float2*)(lpb + (size_t)t * V_ + 2 * lane);
                }
            }
        };
        // block m covers rows u = 4m+1 .. 4m+4; row u lives at slot (u-1)&31
        auto process = [&](float2 (&Rb)[4], int m) {
            // ring-slot reuse gate: slot shared with block m-8
            while (__hip_atomic_load(&cons, __ATOMIC_RELAXED, WG_SCOPE) < 4 * m - 28)
                __builtin_amdgcn_s_sleep(1);
            const int n = min(4, U - 4 * m);
            #pragma unroll
            for (int r = 0; r < 4; ++r) {
                if (r < n) {
                    const float e0 = __builtin_exp2f(Rb[r].x * INV_LN2);
                    const float e1 = __builtin_exp2f(Rb[r].y * INV_LN2);
                    // blank = exp(row[0]) lives in lane 0 (uniform broadcast)
                    const float b0 = __int_as_float(
                        __builtin_amdgcn_readfirstlane(__float_as_int(e0)));
                    float gv[5];
                    #pragma unroll
                    for (int c = 0; c < 5; ++c) {
                        const float lo = __shfl(e0, perm[c], 64);
                        const float hi = __shfl(e1, perm[c], 64);
                        gv[c] = vmask[c] * (oddc[c] ? hi : lo);
                    }
                    float* rb = ring + ((4 * m + r) & (GRING - 1)) * ROWF;
                    ((float2*)rb)[lane]         = make_float2(b0,    gv[0]);
                    ((float2*)(rb + 128))[lane] = make_float2(gv[1], gv[2]);
                    ((float2*)(rb + 256))[lane] = make_float2(gv[3], gv[4]);
                }
            }
            // drain LDS writes only (NOT vmcnt -- prefetched global loads stay
            // in flight), then publish the tag.
            asm volatile("s_waitcnt lgkmcnt(0)" ::: "memory");
            if (lane == 0)
                __hip_atomic_store(&tags[m & 7], m, __ATOMIC_RELAXED, WG_SCOPE);
        };

        int m = q;
        if (4 * m + 1 <= U) {
            issue(R0, m);
            if (4 * (m + NGW) + 1 <= U) issue(R1, m + NGW);
            while (true) {
                process(R0, m);
                if (4 * (m + 2 * NGW) + 1 <= U) issue(R0, m + 2 * NGW);
                m += NGW;
                if (4 * m + 1 > U) break;
                process(R1, m);
                if (4 * (m + 2 * NGW) + 1 <= U) issue(R1, m + 2 * NGW);
                m += NGW;
                if (4 * m + 1 > U) break;
            }
        }
        return;
    }

    // ======================= consumer (wave0) =======================
    float2 S[4][12];                  // [set][row*3+plane], all const-indexed
    auto readBlock = [&](int set, int m) {
        const int base = ((4 * m) & (GRING - 1)) * ROWF + 2 * lane;
        #pragma unroll
        for (int r = 0; r < 4; ++r)
            #pragma unroll
            for (int pl = 0; pl < 3; ++pl)
                S[set][r * 3 + pl] =
                    *(const float2*)&ring[base + r * ROWF + pl * 128];
    };

    if (dir == 0) {
        // -------- forward alpha --------
        float skipf[5];
        #pragma unroll
        for (int c = 0; c < 5; ++c) {
            const int j = 5 * lane + c;
            skipf[c] = (j >= 1 && j < L && tg[j] != tg[j - 1]) ? 1.0f : 0.0f;
        }
        float a[10];
        #pragma unroll
        for (int k = 0; k < 10; ++k) a[k] = 0.0f;
        {
            const float p00 = __builtin_exp2f(lpb[0] * INV_LN2);
            const float p01 = __builtin_exp2f(lpb[tg[0]] * INV_LN2);
            if (lane == 0) { a[0] = p00; a[1] = p01; }
        }
        float u9n = 0.0f;                 // inflow alpha_prev[s-1] for s=10*lane
        int K = 0;

        auto rowCore = [&](float2 c0, float2 c1, float2 c2) {
            const float u9 = u9n;
            const float p0 = c0.x;
            a[9] = (a[9] + a[8] + skipf[4] * a[7]) * c2.y;
            u9n = dpp_mov0<0x138>(a[9]);   // wave_shr:1 (lane0 -> 0), pure VALU
            a[8] = (a[8] + a[7]) * p0;
            a[7] = (a[7] + a[6] + skipf[3] * a[5]) * c2.x;
            a[6] = (a[6] + a[5]) * p0;
            a[5] = (a[5] + a[4] + skipf[2] * a[3]) * c1.y;
            a[4] = (a[4] + a[3]) * p0;
            a[3] = (a[3] + a[2] + skipf[1] * a[1]) * c1.x;
            a[2] = (a[2] + a[1]) * p0;
            a[1] = (a[1] + a[0] + skipf[0] * u9) * c0.y;   // late-consume
            a[0] = (a[0] + u9) * p0;
        };
        auto row4 = [&](int set) {
            #pragma unroll
            for (int r = 0; r < 4; ++r)
                rowCore(S[set][r * 3], S[set][r * 3 + 1], S[set][r * 3 + 2]);
        };
        auto body = [&](int m, int setc, int setp) {
            if (4 * (m + 2) + 1 <= Uf) {
                poll_eq(&tags[(m + 2) & 7], m + 2);
                readBlock(setp, m + 2);
            }
            row4(setc);
            if (lane == 0)
                __hip_atomic_store(&cons, 4 * m + 4, __ATOMIC_RELAXED, WG_SCOPE);
        };

        const int MB4 = (Uf / 4) & ~3;
        poll_eq(&tags[0], 0); readBlock(0, 0);
        poll_eq(&tags[1], 1); readBlock(1, 1);
        for (int mb = 0; mb < MB4; mb += 4) {
            body(mb + 0, 0, 2);
            body(mb + 1, 1, 3);
            { const int ks = wave_rescale(a, K); u9n = ldexpf(u9n, ks); }  // 8 rows
            body(mb + 2, 2, 0);
            body(mb + 3, 3, 1);
            { const int ks = wave_rescale(a, K); u9n = ldexpf(u9n, ks); }  // 8 rows
        }
        // tail: blocks MB4 (set0), MB4+1 (set1) partially, then direct ring rows
        #pragma unroll
        for (int r = 0; r < 4; ++r)
            if (4 * MB4 + 1 + r <= Uf)
                rowCore(S[0][r * 3], S[0][r * 3 + 1], S[0][r * 3 + 2]);
        #pragma unroll
        for (int r = 0; r < 4; ++r)
            if (4 * MB4 + 5 + r <= Uf)
                rowCore(S[1][r * 3], S[1][r * 3 + 1], S[1][r * 3 + 2]);
        { const int ks = wave_rescale(a, K); u9n = ldexpf(u9n, ks); }      // <=8 rows
        for (int u = 4 * MB4 + 9; u <= Uf; ++u) {                          // <=7 rows
            const int bu = (u - 1) >> 2;
            poll_eq(&tags[bu & 7], bu);
            const int base = ((u - 1) & (GRING - 1)) * ROWF + 2 * lane;
            const float2 c0 = *(const float2*)&ring[base];
            const float2 c1 = *(const float2*)&ring[base + 128];
            const float2 c2 = *(const float2*)&ring[base + 256];
            rowCore(c0, c1, c2);
        }

        float* dump = WS_DUMPF(W, b);
        #pragma unroll
        for (int k = 0; k < 10; ++k) dump[10 * lane + k] = a[k];
        if (lane == 0) WS_KARR(W)[b] = K;
    } else {
        // -------- backward beta --------
        float sB[5];                  // skip into s+2 (odd): label j = 5*lane+c+1
        #pragma unroll
        for (int c = 0; c < 5; ++c) {
            const int j = 5 * lane + c + 1;
            sB[c] = (j < L && tg[j] != tg[j - 1]) ? 1.0f : 0.0f;
        }
        float g[10];
        #pragma unroll
        for (int k = 0; k < 10; ++k) g[k] = 0.0f;
        {   // g_{Tb-1}: nonzero at s=2L (blank) and s=2L-1 (last label)
            const float pb = __builtin_exp2f(lpb[(size_t)(Tb - 1) * V_] * INV_LN2);
            const float pl = __builtin_exp2f(lpb[(size_t)(Tb - 1) * V_ + tg[L - 1]] * INV_LN2);
            #pragma unroll
            for (int k = 0; k < 10; ++k) {
                const int s = 10 * lane + k;
                if (s == 2 * L)     g[k] = pb;
                if (s == 2 * L - 1) g[k] = pl;
            }
        }
        float d0n = dpp_mov0<0x130>(g[0]);   // wave_shl:1 (lane63 -> 0)
        float d1n = dpp_mov0<0x130>(g[1]);
        int K = 0;

        auto rowCore = [&](float2 c0, float2 c1, float2 c2) {
            const float d0 = d0n, d1 = d1n;
            const float p0 = c0.x;
            g[0] = (g[0] + g[1]) * p0;
            g[1] = (g[1] + g[2] + sB[0] * g[3]) * c0.y;
            d0n = dpp_mov0<0x130>(g[0]);     // early-produce, pure VALU
            d1n = dpp_mov0<0x130>(g[1]);
            g[2] = (g[2] + g[3]) * p0;
            g[3] = (g[3] + g[4] + sB[1] * g[5]) * c1.x;
            g[4] = (g[4] + g[5]) * p0;
            g[5] = (g[5] + g[6] + sB[2] * g[7]) * c1.y;
            g[6] = (g[6] + g[7]) * p0;
            g[7] = (g[7] + g[8] + sB[3] * g[9]) * c2.x;
            g[8] = (g[8] + g[9]) * p0;
            g[9] = (g[9] + d0 + sB[4] * d1) * c2.y;      // late-consume
        };
        auto row4 = [&](int set) {
            #pragma unroll
            for (int r = 0; r < 4; ++r)
                rowCore(S[set][r * 3], S[set][r * 3 + 1], S[set][r * 3 + 2]);
        };
        auto body = [&](int m, int setc, int setp) {
            if (4 * (m + 2) + 1 <= Ub) {
                poll_eq(&tags[(m + 2) & 7], m + 2);
                readBlock(setp, m + 2);
            }
            row4(setc);
            if (lane == 0)
                __hip_atomic_store(&cons, 4 * m + 4, __ATOMIC_RELAXED, WG_SCOPE);
        };

        const int MB4 = (Ub / 4) & ~3;
        poll_eq(&tags[0], 0); readBlock(0, 0);
        poll_eq(&tags[1], 1); readBlock(1, 1);
        for (int mb = 0; mb < MB4; mb += 4) {
            body(mb + 0, 0, 2);
            body(mb + 1, 1, 3);
            { const int ks = wave_rescale(g, K);
              d0n = ldexpf(d0n, ks); d1n = ldexpf(d1n, ks); }
            body(mb + 2, 2, 0);
            body(mb + 3, 3, 1);
            { const int ks = wave_rescale(g, K);
              d0n = ldexpf(d0n, ks); d1n = ldexpf(d1n, ks); }
        }
        #pragma unroll
        for (int r = 0; r < 4; ++r)
            if (4 * MB4 + 1 + r <= Ub)
                rowCore(S[0][r * 3], S[0][r * 3 + 1], S[0][r * 3 + 2]);
        #pragma unroll
        for (int r = 0; r < 4; ++r)
            if (4 * MB4 + 5 + r <= Ub)
                rowCore(S[1][r * 3], S[1][r * 3 + 1], S[1][r * 3 + 2]);
        { const int ks = wave_rescale(g, K);
          d0n = ldexpf(d0n, ks); d1n = ldexpf(d1n, ks); }
        for (int u = 4 * MB4 + 9; u <= Ub; ++u) {
            const int bu = (u - 1) >> 2;
            poll_eq(&tags[bu & 7], bu);
            const int base = ((u - 1) & (GRING - 1)) * ROWF + 2 * lane;
            const float2 c0 = *(const float2*)&ring[base];
            const float2 c1 = *(const float2*)&ring[base + 128];
            const float2 c2 = *(const float2*)&ring[base + 256];
            rowCore(c0, c1, c2);
        }

        {   // combine: gext[s] = g[s] + g[s+1] + skip[s+2]*g[s+2] (ascending)
            const float d0 = d0n, d1 = d1n;
            g[0] = g[0] + g[1];
            g[1] = g[1] + g[2] + sB[0] * g[3];
            g[2] = g[2] + g[3];
            g[3] = g[3] + g[4] + sB[1] * g[5];
            g[4] = g[4] + g[5];
            g[5] = g[5] + g[6] + sB[2] * g[7];
            g[6] = g[6] + g[7];
            g[7] = g[7] + g[8] + sB[3] * g[9];
            g[8] = g[8] + g[9];
            g[9] = g[9] + d0 + sB[4] * d1;
        }
        float* dump = WS_DUMPB(W, b);
        #pragma unroll
        for (int k = 0; k < 10; ++k) dump[10 * lane + k] = g[k];
        if (lane == 0) WS_KARR(W)[64 + b] = K;
    }
}

// Join: one block per batch element, 64 lanes. Double-precision dot of the
// two dumps (factors span ~240 bits in f32 frames -- R7 lesson).
__global__ void ctc_join_kernel(const float* __restrict__ W_const,
                                const int* __restrict__ tgt_len,
                                float* __restrict__ lossArr) {
    const int b = blockIdx.x;
    const int lane = threadIdx.x;
    float* W = const_cast<float*>(W_const);
    const float* dA = WS_DUMPF(W, b);
    const float* dB = WS_DUMPB(W, b);
    double sum = 0.0;
    #pragma unroll
    for (int k = 0; k < 10; ++k)
        sum += (double)dA[10 * lane + k] * (double)dB[10 * lane + k];
    #pragma unroll
    for (int d = 1; d < 64; d <<= 1) sum += __shfl_xor(sum, d, 64);
    if (lane == 0) {
        const int L = tgt_len[b];
        const int KF = WS_KARR(W)[b];
        const int KB = WS_KARR(W)[64 + b];
        float loss = 0.0f;                     // infeasible (sum<=0) -> 0
        if (sum > 0.0) {
            const long long ub = __double_as_longlong(sum);
            const int ex = (int)((ub >> 52) & 2047) - 1023;
            const double f = __longlong_as_double(
                (ub & 0x000FFFFFFFFFFFFFLL) | 0x3FF0000000000000LL);
            const float ll2 = __builtin_log2f((float)f)
                            + (float)(ex - KF - KB);
            loss = -(ll2 * LN2);
            if (!(loss <= 1e29f)) loss = 0.0f; // zero_infinity
        }
        lossArr[b] = loss / (float)L;
    }
}

__global__ void ctc_reduce_kernel(const float* __restrict__ ws, float* __restrict__ out) {
    float v = ws[threadIdx.x];
    #pragma unroll
    for (int o = 32; o > 0; o >>= 1) v += __shfl_down(v, o);
    if (threadIdx.x == 0) out[0] = v / (float)B_;
}

extern "C" void kernel_launch(void* const* d_in, const int* in_sizes, int n_in,
                              void* d_out, int out_size, void* d_ws, size_t ws_size,
                              hipStream_t stream) {
    const float* lp      = (const float*)d_in[0];
    const int*   in_len  = (const int*)d_in[1];
    const int*   tgt     = (const int*)d_in[2];
    const int*   tgt_len = (const int*)d_in[3];
    float* W   = (float*)d_ws;                  // needs ~330 KB
    float* out = (float*)d_out;

    ctc_scan<<<2 * B_, 256, 0, stream>>>(lp, in_len, tgt, tgt_len, W);
    ctc_join_kernel<<<B_, 64, 0, stream>>>(W, tgt_len, W);   // writes W[0..63]
    ctc_reduce_kernel<<<1, 64, 0, stream>>>(W, out);
}